// Round 12
// baseline (439.723 us; speedup 1.0000x reference)
//
#include <hip/hip_runtime.h>

// CircuitModel: sequential Oja/Hebbian plasticity scan.
//   y_t = sigmoid(w_t.x_t); w_{t+1} = b_t*w_t + a_t*x_t,
//   a_t = lr*th0*y_t, b_t = 1 + lr*th1*y_t^2; out[t,p] = y_t at observed rows.
//
// R1: __shfl_xor = LDS swizzle ~120cy/step -> DPP reduce.
// R2: readlane is int(int,int) — must bitcast.
// R3-R6: compiler collapsed every register prefetch pipeline.
// R7-R9: LDS pipelines stuck ~390us (store drain + 4x LDS pipe re-read).
// R10: asm loads + tied vmcnt(1): 300us; scheduler hoisted compute above
//     the prefetch (only asm is volatile-ordered).
// R11: PIN (empty tying asm) pinned compute between load-issue and wait:
//     234us scan = 1480cy issue + ~700cy sigmoid-chain bubbles per block.
//     Memory is now off the critical path; kernel is per-wave issue+chain
//     bound with ONE wave per SIMD (bubbles = idle SIMD).
// R12: co-schedule 2 waves/SIMD (32 WGs x 512 thr; 8 waves/WG -> 2/SIMD).
//     Each wave's issue fills the other's chain bubbles (m114: co-resident
//     waves overlap ~max not sum). Register fit: ~84 VGPR + ~64 AGPR = 148
//     <= 256/wave at 2 waves/SIMD.

constexpr int N_IN    = 512;
constexpr int T       = 2048;
constexpr int N_OBS   = 256;
constexpr int D       = 8;            // linearization block size
constexpr int NBLK    = T / D;        // 256
constexpr int BANDPAD = 64;           // packed-band floats per block (28 used)

typedef float f4 __attribute__((ext_vector_type(4)));

// Packed band layout for block b (t0=8b): entry k = x_{t0+i}.x_{t0+i+j},
// k = BOFF[i] + (j-1), i=0..6, j=1..7-i (28 entries).
__device__ constexpr int BOFF[8] = {0, 7, 13, 18, 22, 25, 27, 28};

// DPP add-reduce step; old=0 is the additive identity for invalid lanes.
#define DPP_ADD(v, ctrl, rmask)                                                \
    v += __int_as_float(__builtin_amdgcn_update_dpp(                           \
        0, __float_as_int(v), (ctrl), (rmask), 0xf, false))

__device__ __forceinline__ float wave64_sum_bcast(float v) {
    DPP_ADD(v, 0x111, 0xf); // row_shr:1
    DPP_ADD(v, 0x112, 0xf); // row_shr:2
    DPP_ADD(v, 0x114, 0xf); // row_shr:4
    DPP_ADD(v, 0x118, 0xf); // row_shr:8
    DPP_ADD(v, 0x142, 0xa); // row_bcast:15
    DPP_ADD(v, 0x143, 0xc); // row_bcast:31 -> lane63 = total
    return __int_as_float(__builtin_amdgcn_readlane(__float_as_int(v), 63));
}

__device__ __forceinline__ float dot8(const f4& u0, const f4& u1,
                                      const f4& v0, const f4& v1) {
    float p0 = fmaf(u0.x, v0.x, u0.y * v0.y);
    float p1 = fmaf(u0.z, v0.z, u0.w * v0.w);
    float p2 = fmaf(u1.x, v1.x, u1.y * v1.y);
    float p3 = fmaf(u1.z, v1.z, u1.w * v1.w);
    return (p0 + p1) + (p2 + p3);
}

// ---- explicit-VMEM primitives ---------------------------------------------
#define GLOADX(dst, addr, offstr)                                              \
    asm volatile("global_load_dwordx4 %0, %1, off offset:" offstr              \
                 : "=v"(dst) : "v"(addr))

// Stage one block's 8 x-rows: exactly 16 vmem load issues, program-ordered.
__device__ __forceinline__ void stage16(f4 (&xb)[16], const char* xa) {
    const char* a0 = xa;
    const char* a1 = xa + 4096;
    const char* a2 = xa + 8192;
    const char* a3 = xa + 12288;
    GLOADX(xb[0],  a0, "0");    GLOADX(xb[1],  a0, "1024");
    GLOADX(xb[2],  a0, "2048"); GLOADX(xb[3],  a0, "3072");
    GLOADX(xb[4],  a1, "0");    GLOADX(xb[5],  a1, "1024");
    GLOADX(xb[6],  a1, "2048"); GLOADX(xb[7],  a1, "3072");
    GLOADX(xb[8],  a2, "0");    GLOADX(xb[9],  a2, "1024");
    GLOADX(xb[10], a2, "2048"); GLOADX(xb[11], a2, "3072");
    GLOADX(xb[12], a3, "0");    GLOADX(xb[13], a3, "1024");
    GLOADX(xb[14], a3, "2048"); GLOADX(xb[15], a3, "3072");
}

#define TIEBUF(ins, buf)                                                       \
    asm volatile(ins                                                           \
        : "+v"(buf[0]), "+v"(buf[1]), "+v"(buf[2]),  "+v"(buf[3]),             \
          "+v"(buf[4]), "+v"(buf[5]), "+v"(buf[6]),  "+v"(buf[7]),             \
          "+v"(buf[8]), "+v"(buf[9]), "+v"(buf[10]), "+v"(buf[11]),            \
          "+v"(buf[12]),"+v"(buf[13]),"+v"(buf[14]), "+v"(buf[15]))

// Pin: consumers of buf must schedule after this point (dataflow), and this
// point is after the preceding volatile loads (volatile order). Zero insts.
#define PIN(buf)      TIEBUF("", buf)
// Wait: drain all but the newest N outstanding vmem ops, tying buf's values.
#define WAIT1(buf)    TIEBUF("s_waitcnt vmcnt(1)", buf)
#define WAIT0(buf)    TIEBUF("s_waitcnt vmcnt(0)", buf)

// ---- Kernel 1: packed Gram band, one wave per 8-step block -----------------
__global__ __launch_bounds__(64) void gram_kernel(const float* __restrict__ X,
                                                  float* __restrict__ P) {
    const int b    = blockIdx.x;          // 0..NBLK-1
    const int lane = threadIdx.x;         // 0..63
    const int t0   = b * D;
    const f4* Xv = (const f4*)(X + (long)t0 * N_IN);
    f4 r[8][2];
    #pragma unroll
    for (int i = 0; i < 8; ++i) {
        r[i][0] = Xv[i * (N_IN / 4) + lane * 2 + 0];
        r[i][1] = Xv[i * (N_IN / 4) + lane * 2 + 1];
    }
    float s[28];
    #pragma unroll
    for (int i = 0; i < 7; ++i) {
        #pragma unroll
        for (int j = 1; j <= 7 - i; ++j) {
            s[BOFF[i] + j - 1] =
                wave64_sum_bcast(dot8(r[i][0], r[i][1], r[i + j][0], r[i + j][1]));
        }
    }
    if (lane == 0) {
        #pragma unroll
        for (int k = 0; k < 28; ++k) P[b * BANDPAD + k] = s[k];
    }
}

// ---- process one block from a register buffer ------------------------------
__device__ __forceinline__ void process_block(
    const f4 (&xb)[16], const float (&bs)[28], int t0, int lane, int wave,
    f4& w0, f4& w1, float th0, float th1, float* __restrict__ out)
{
    // Boundary: Q_d = w_{t0} . x_{t0+d} (8 independent DPP chains).
    float q[D];
    #pragma unroll
    for (int d = 0; d < D; ++d)
        q[d] = wave64_sum_bcast(dot8(w0, w1, xb[2 * d], xb[2 * d + 1]));

    // Eight steps: sigmoid + Q propagation + rank-1 w update.
    float ys = 0.0f;
    float z = q[0];
    #pragma unroll
    for (int i = 0; i < D; ++i) {
        const float y = __builtin_amdgcn_rcpf(1.0f + __expf(-z));
        if (lane == i) ys = y;

        const float a = th0 * y;
        const float b = fmaf(th1 * y, y, 1.0f);

        #pragma unroll
        for (int d = i + 1; d < D; ++d)
            q[d] = fmaf(b, q[d], a * bs[BOFF[i] + (d - i) - 1]);
        if (i < D - 1) z = q[i + 1];

        w0.x = fmaf(b, w0.x, a * xb[2 * i].x);
        w0.y = fmaf(b, w0.y, a * xb[2 * i].y);
        w0.z = fmaf(b, w0.z, a * xb[2 * i].z);
        w0.w = fmaf(b, w0.w, a * xb[2 * i].w);
        w1.x = fmaf(b, w1.x, a * xb[2 * i + 1].x);
        w1.y = fmaf(b, w1.y, a * xb[2 * i + 1].y);
        w1.z = fmaf(b, w1.z, a * xb[2 * i + 1].z);
        w1.w = fmaf(b, w1.w, a * xb[2 * i + 1].w);
    }

    // One batched store: lanes 0..7 write y_0..y_7 (exec-masked). Volatile:
    // stays before the following WAIT1, pinning the y dep-chain with it.
    float* oaddr = out + (size_t)(t0 + lane) * N_OBS + wave;
    asm volatile("s_mov_b64 vcc, exec\n\t"
                 "s_mov_b64 exec, 0xff\n\t"
                 "global_store_dword %0, %1, off\n\t"
                 "s_mov_b64 exec, vcc"
                 :: "v"(oaddr), "v"(ys) : "vcc");
}

__device__ __forceinline__ void load_band(float (&bs)[28], const float* pb) {
    #pragma unroll
    for (int k = 0; k < 28; ++k) bs[k] = pb[k];   // wave-uniform -> s_load
}

// ---- Kernel 2: the scan ----------------------------------------------------
__global__ __launch_bounds__(512, 1) void oja_scan_kernel(
    const float* __restrict__ X,     // [T, N_IN]
    const float* __restrict__ Winit, // [N_OUT, N_IN]
    const float* __restrict__ theta, // [2]
    const int*   __restrict__ obs,   // [N_OBS]
    const float* __restrict__ P,     // [NBLK, BANDPAD] packed band (d_ws)
    float*       __restrict__ out)   // [T, N_OBS]
{
    const int tid  = threadIdx.x;
    const int wid  = tid >> 6;            // 0..7 (8 waves -> 2 per SIMD)
    const int lane = tid & 63;
    const int wave = blockIdx.x * 8 + wid; // observed-row index; always < 256

    const int row = obs[wave];
    const float lr  = 1.0f / (float)N_IN;
    const float th0 = theta[0] * lr;
    const float th1 = theta[1] * lr;

    // Ownership (R8): lane owns elements [4l,4l+4) and [256+4l,256+4l+4).
    const f4* Wv = (const f4*)(Winit + (long)row * N_IN);
    f4 w0 = Wv[lane];
    f4 w1 = Wv[64 + lane];

    const char* xbase = (const char*)X + (size_t)lane * 16;

    f4 xA[16], xB[16];
    float bsA[28], bsB[28];

    // Prologue: block 0 into A, full drain.
    stage16(xA, xbase);
    load_band(bsA, P);
    WAIT0(xA);

    for (int blk = 0; blk < NBLK; blk += 2) {
        // Half 1: stage blk+1 into B; PIN(A) forces process(A)'s compute
        // after the loads; WAIT1 drains B's 16 loads (issued ~1 block ago),
        // leaving only the newest out-store in flight.
        const int b1 = (blk + 1 < NBLK) ? (blk + 1) : (NBLK - 1);
        stage16(xB, xbase + (size_t)b1 * 16384);
        load_band(bsB, P + (size_t)b1 * BANDPAD);
        PIN(xA);
        process_block(xA, bsA, blk * D, lane, wave, w0, w1, th0, th1, out);
        WAIT1(xB);

        // Half 2: symmetric.
        const int b2 = (blk + 2 < NBLK) ? (blk + 2) : (NBLK - 1);
        stage16(xA, xbase + (size_t)b2 * 16384);
        load_band(bsA, P + (size_t)b2 * BANDPAD);
        PIN(xB);
        process_block(xB, bsB, (blk + 1) * D, lane, wave, w0, w1, th0, th1, out);
        WAIT1(xA);
    }
}

extern "C" void kernel_launch(void* const* d_in, const int* in_sizes, int n_in,
                              void* d_out, int out_size, void* d_ws, size_t ws_size,
                              hipStream_t stream) {
    const float* X     = (const float*)d_in[0];
    const float* Winit = (const float*)d_in[1];
    const float* theta = (const float*)d_in[2];
    const int*   obs   = (const int*)d_in[3];
    float*       out   = (float*)d_out;
    float*       P     = (float*)d_ws;   // NBLK*BANDPAD floats = 64 KB

    // Gram band: one wave per block.
    gram_kernel<<<NBLK, 64, 0, stream>>>(X, P);

    // Scan: 32 workgroups x 8 waves = 256 waves, 2 waves per SIMD so each
    // wave's issue fills the other's sigmoid-chain bubbles.
    oja_scan_kernel<<<32, 512, 0, stream>>>(X, Winit, theta, obs, P, out);
}

// Round 13
// 319.896 us; speedup vs baseline: 1.3746x; 1.3746x over previous
//
#include <hip/hip_runtime.h>

// CircuitModel: sequential Oja/Hebbian plasticity scan.
//   y_t = sigmoid(w_t.x_t); w_{t+1} = b_t*w_t + a_t*x_t,
//   a_t = lr*th0*y_t, b_t = 1 + lr*th1*y_t^2; out[t,p] = y_t at observed rows.
//
// R1: __shfl_xor = LDS swizzle ~120cy/step -> DPP reduce.
// R2: readlane is int(int,int) — must bitcast.
// R3-R6: compiler collapsed every register prefetch pipeline.
// R7-R9: LDS pipelines stuck ~390us (store drain + 4x LDS pipe re-read).
// R10: asm loads + tied vmcnt(1): 300us; compute hoisted above prefetch.
// R11: PIN pinned compute between load-issue and wait: 234us scan
//     (~1480cy issue + ~700cy sigmoid-chain bubbles per block).
// R12 REGRESSION (383us): 2 waves/SIMD halves active CUs; issue demand
//     2x1480 > 2194 wall. With 256 fixed waves, 1 wave/SIMD is optimal;
//     the lever is CUTTING PER-WAVE ISSUE COUNT.
// R13: revert to 64WGx256 + packed FP32 (v_pk_mul/fma_f32, tied inline asm):
//     dot8 11->6 insts, w-update 16->~12 insts/step. Issue ~740->~450 insts.

constexpr int N_IN    = 512;
constexpr int T       = 2048;
constexpr int N_OBS   = 256;
constexpr int D       = 8;            // linearization block size
constexpr int NBLK    = T / D;        // 256
constexpr int BANDPAD = 64;           // packed-band floats per block (28 used)

typedef float f4 __attribute__((ext_vector_type(4)));
typedef float f2 __attribute__((ext_vector_type(2)));

// Packed band layout for block b (t0=8b): entry k = x_{t0+i}.x_{t0+i+j},
// k = BOFF[i] + (j-1), i=0..6, j=1..7-i (28 entries).
__device__ constexpr int BOFF[8] = {0, 7, 13, 18, 22, 25, 27, 28};

// ---- packed-FP32 primitives (dataflow-ordered inline asm) ------------------
#define PK_MUL(d, s0, s1)                                                      \
    asm("v_pk_mul_f32 %0, %1, %2" : "=v"(d) : "v"(s0), "v"(s1))
#define PK_ADD(d, s0, s1)                                                      \
    asm("v_pk_add_f32 %0, %1, %2" : "=v"(d) : "v"(s0), "v"(s1))
// d = s0*s1 + d
#define PK_FMA(d, s0, s1)                                                      \
    asm("v_pk_fma_f32 %0, %1, %2, %0" : "+v"(d) : "v"(s0), "v"(s1))
// d = m*d + t
#define PK_FMA3(d, m, t)                                                       \
    asm("v_pk_fma_f32 %0, %1, %0, %2" : "+v"(d) : "v"(m), "v"(t))

// DPP add-reduce step; old=0 is the additive identity for invalid lanes.
#define DPP_ADD(v, ctrl, rmask)                                                \
    v += __int_as_float(__builtin_amdgcn_update_dpp(                           \
        0, __float_as_int(v), (ctrl), (rmask), 0xf, false))

__device__ __forceinline__ float wave64_sum_bcast(float v) {
    DPP_ADD(v, 0x111, 0xf); // row_shr:1
    DPP_ADD(v, 0x112, 0xf); // row_shr:2
    DPP_ADD(v, 0x114, 0xf); // row_shr:4
    DPP_ADD(v, 0x118, 0xf); // row_shr:8
    DPP_ADD(v, 0x142, 0xa); // row_bcast:15
    DPP_ADD(v, 0x143, 0xc); // row_bcast:31 -> lane63 = total
    return __int_as_float(__builtin_amdgcn_readlane(__float_as_int(v), 63));
}

// Scalar dot8 (gram kernel only; off the critical path).
__device__ __forceinline__ float dot8(const f4& u0, const f4& u1,
                                      const f4& v0, const f4& v1) {
    float p0 = fmaf(u0.x, v0.x, u0.y * v0.y);
    float p1 = fmaf(u0.z, v0.z, u0.w * v0.w);
    float p2 = fmaf(u1.x, v1.x, u1.y * v1.y);
    float p3 = fmaf(u1.z, v1.z, u1.w * v1.w);
    return (p0 + p1) + (p2 + p3);
}

// Packed dot8: w (4 x f2) . x-slice (2 x f4) -> lane-partial scalar. 6 insts.
__device__ __forceinline__ float dot8pk(const f2 (&w)[4],
                                        const f4& x0, const f4& x1) {
    f2 a0 = {x0.x, x0.y}, a1 = {x0.z, x0.w};
    f2 a2 = {x1.x, x1.y}, a3 = {x1.z, x1.w};
    f2 p0, p1;
    PK_MUL(p0, w[0], a0);
    PK_FMA(p0, w[1], a1);
    PK_MUL(p1, w[2], a2);
    PK_FMA(p1, w[3], a3);
    PK_ADD(p0, p0, p1);
    return p0.x + p0.y;
}

// ---- explicit-VMEM primitives ---------------------------------------------
#define GLOADX(dst, addr, offstr)                                              \
    asm volatile("global_load_dwordx4 %0, %1, off offset:" offstr              \
                 : "=v"(dst) : "v"(addr))

// Stage one block's 8 x-rows: exactly 16 vmem load issues, program-ordered.
__device__ __forceinline__ void stage16(f4 (&xb)[16], const char* xa) {
    const char* a0 = xa;
    const char* a1 = xa + 4096;
    const char* a2 = xa + 8192;
    const char* a3 = xa + 12288;
    GLOADX(xb[0],  a0, "0");    GLOADX(xb[1],  a0, "1024");
    GLOADX(xb[2],  a0, "2048"); GLOADX(xb[3],  a0, "3072");
    GLOADX(xb[4],  a1, "0");    GLOADX(xb[5],  a1, "1024");
    GLOADX(xb[6],  a1, "2048"); GLOADX(xb[7],  a1, "3072");
    GLOADX(xb[8],  a2, "0");    GLOADX(xb[9],  a2, "1024");
    GLOADX(xb[10], a2, "2048"); GLOADX(xb[11], a2, "3072");
    GLOADX(xb[12], a3, "0");    GLOADX(xb[13], a3, "1024");
    GLOADX(xb[14], a3, "2048"); GLOADX(xb[15], a3, "3072");
}

#define TIEBUF(ins, buf)                                                       \
    asm volatile(ins                                                           \
        : "+v"(buf[0]), "+v"(buf[1]), "+v"(buf[2]),  "+v"(buf[3]),             \
          "+v"(buf[4]), "+v"(buf[5]), "+v"(buf[6]),  "+v"(buf[7]),             \
          "+v"(buf[8]), "+v"(buf[9]), "+v"(buf[10]), "+v"(buf[11]),            \
          "+v"(buf[12]),"+v"(buf[13]),"+v"(buf[14]), "+v"(buf[15]))

// Pin: consumers of buf must schedule after this point (dataflow), and this
// point is after the preceding volatile loads (volatile order). Zero insts.
#define PIN(buf)      TIEBUF("", buf)
// Wait: drain all but the newest N outstanding vmem ops, tying buf's values.
#define WAIT1(buf)    TIEBUF("s_waitcnt vmcnt(1)", buf)
#define WAIT0(buf)    TIEBUF("s_waitcnt vmcnt(0)", buf)

// ---- Kernel 1: packed Gram band, one wave per 8-step block -----------------
__global__ __launch_bounds__(64) void gram_kernel(const float* __restrict__ X,
                                                  float* __restrict__ P) {
    const int b    = blockIdx.x;          // 0..NBLK-1
    const int lane = threadIdx.x;         // 0..63
    const int t0   = b * D;
    const f4* Xv = (const f4*)(X + (long)t0 * N_IN);
    f4 r[8][2];
    #pragma unroll
    for (int i = 0; i < 8; ++i) {
        r[i][0] = Xv[i * (N_IN / 4) + lane * 2 + 0];
        r[i][1] = Xv[i * (N_IN / 4) + lane * 2 + 1];
    }
    float s[28];
    #pragma unroll
    for (int i = 0; i < 7; ++i) {
        #pragma unroll
        for (int j = 1; j <= 7 - i; ++j) {
            s[BOFF[i] + j - 1] =
                wave64_sum_bcast(dot8(r[i][0], r[i][1], r[i + j][0], r[i + j][1]));
        }
    }
    if (lane == 0) {
        #pragma unroll
        for (int k = 0; k < 28; ++k) P[b * BANDPAD + k] = s[k];
    }
}

// ---- process one block from a register buffer ------------------------------
__device__ __forceinline__ void process_block(
    const f4 (&xb)[16], const float (&bs)[28], int t0, int lane, int wave,
    f2 (&w)[4], float th0, float th1, float* __restrict__ out)
{
    // Boundary: Q_d = w_{t0} . x_{t0+d} (8 independent DPP chains).
    float q[D];
    #pragma unroll
    for (int d = 0; d < D; ++d)
        q[d] = wave64_sum_bcast(dot8pk(w, xb[2 * d], xb[2 * d + 1]));

    // Eight steps: sigmoid + Q propagation + packed rank-1 w update.
    float ys = 0.0f;
    float z = q[0];
    #pragma unroll
    for (int i = 0; i < D; ++i) {
        const float y = __builtin_amdgcn_rcpf(1.0f + __expf(-z));
        if (lane == i) ys = y;

        const float a = th0 * y;
        const float b = fmaf(th1 * y, y, 1.0f);

        #pragma unroll
        for (int d = i + 1; d < D; ++d)
            q[d] = fmaf(b, q[d], a * bs[BOFF[i] + (d - i) - 1]);
        if (i < D - 1) z = q[i + 1];

        // w = b*w + a*x, packed: per f2 chunk t = a2*x; w = b2*w + t.
        const f2 a2 = {a, a};
        const f2 b2 = {b, b};
        const f4& xlo = xb[2 * i];
        const f4& xhi = xb[2 * i + 1];
        f2 c0 = {xlo.x, xlo.y}, c1 = {xlo.z, xlo.w};
        f2 c2 = {xhi.x, xhi.y}, c3 = {xhi.z, xhi.w};
        f2 t0v, t1v, t2v, t3v;
        PK_MUL(t0v, a2, c0);  PK_MUL(t1v, a2, c1);
        PK_MUL(t2v, a2, c2);  PK_MUL(t3v, a2, c3);
        PK_FMA3(w[0], b2, t0v);
        PK_FMA3(w[1], b2, t1v);
        PK_FMA3(w[2], b2, t2v);
        PK_FMA3(w[3], b2, t3v);
    }

    // One batched store: lanes 0..7 write y_0..y_7 (exec-masked). Volatile:
    // stays before the following WAIT1, pinning the y dep-chain with it.
    float* oaddr = out + (size_t)(t0 + lane) * N_OBS + wave;
    asm volatile("s_mov_b64 vcc, exec\n\t"
                 "s_mov_b64 exec, 0xff\n\t"
                 "global_store_dword %0, %1, off\n\t"
                 "s_mov_b64 exec, vcc"
                 :: "v"(oaddr), "v"(ys) : "vcc");
}

__device__ __forceinline__ void load_band(float (&bs)[28], const float* pb) {
    #pragma unroll
    for (int k = 0; k < 28; ++k) bs[k] = pb[k];   // wave-uniform -> s_load
}

// ---- Kernel 2: the scan ----------------------------------------------------
__global__ __launch_bounds__(256, 1) void oja_scan_kernel(
    const float* __restrict__ X,     // [T, N_IN]
    const float* __restrict__ Winit, // [N_OUT, N_IN]
    const float* __restrict__ theta, // [2]
    const int*   __restrict__ obs,   // [N_OBS]
    const float* __restrict__ P,     // [NBLK, BANDPAD] packed band (d_ws)
    float*       __restrict__ out)   // [T, N_OBS]
{
    const int tid  = threadIdx.x;
    const int wid  = tid >> 6;            // 0..3 (1 wave per SIMD)
    const int lane = tid & 63;
    const int wave = blockIdx.x * 4 + wid; // observed-row index; always < 256

    const int row = obs[wave];
    const float lr  = 1.0f / (float)N_IN;
    const float th0 = theta[0] * lr;
    const float th1 = theta[1] * lr;

    // Ownership (R8): lane owns elements [4l,4l+4) and [256+4l,256+4l+4),
    // held as 4 f2 chunks for packed math.
    const f4* Wv = (const f4*)(Winit + (long)row * N_IN);
    const f4 wa = Wv[lane];
    const f4 wb = Wv[64 + lane];
    f2 w[4] = { {wa.x, wa.y}, {wa.z, wa.w}, {wb.x, wb.y}, {wb.z, wb.w} };

    const char* xbase = (const char*)X + (size_t)lane * 16;

    f4 xA[16], xB[16];
    float bsA[28], bsB[28];

    // Prologue: block 0 into A, full drain.
    stage16(xA, xbase);
    load_band(bsA, P);
    WAIT0(xA);

    for (int blk = 0; blk < NBLK; blk += 2) {
        // Half 1: stage blk+1 into B; PIN(A) forces process(A)'s compute
        // after the loads; WAIT1 drains B's 16 loads (issued ~1 block ago),
        // leaving only the newest out-store in flight.
        const int b1 = (blk + 1 < NBLK) ? (blk + 1) : (NBLK - 1);
        stage16(xB, xbase + (size_t)b1 * 16384);
        load_band(bsB, P + (size_t)b1 * BANDPAD);
        PIN(xA);
        process_block(xA, bsA, blk * D, lane, wave, w, th0, th1, out);
        WAIT1(xB);

        // Half 2: symmetric.
        const int b2 = (blk + 2 < NBLK) ? (blk + 2) : (NBLK - 1);
        stage16(xA, xbase + (size_t)b2 * 16384);
        load_band(bsA, P + (size_t)b2 * BANDPAD);
        PIN(xB);
        process_block(xB, bsB, (blk + 1) * D, lane, wave, w, th0, th1, out);
        WAIT1(xA);
    }
}

extern "C" void kernel_launch(void* const* d_in, const int* in_sizes, int n_in,
                              void* d_out, int out_size, void* d_ws, size_t ws_size,
                              hipStream_t stream) {
    const float* X     = (const float*)d_in[0];
    const float* Winit = (const float*)d_in[1];
    const float* theta = (const float*)d_in[2];
    const int*   obs   = (const int*)d_in[3];
    float*       out   = (float*)d_out;
    float*       P     = (float*)d_ws;   // NBLK*BANDPAD floats = 64 KB

    // Gram band: one wave per block.
    gram_kernel<<<NBLK, 64, 0, stream>>>(X, P);

    // Scan: 64 WGs x 4 waves = 256 waves, one per SIMD on 64 CUs (R11 shape).
    oja_scan_kernel<<<64, 256, 0, stream>>>(X, Winit, theta, obs, P, out);
}

// Round 15
// 249.290 us; speedup vs baseline: 1.7639x; 1.2832x over previous
//
#include <hip/hip_runtime.h>

// CircuitModel: sequential Oja/Hebbian plasticity scan.
//   y_t = sigmoid(w_t.x_t); w_{t+1} = b_t*w_t + a_t*x_t,
//   a_t = lr*th0*y_t, b_t = 1 + lr*th1*y_t^2; out[t,p] = y_t at observed rows.
//
// R1: __shfl_xor = LDS swizzle ~120cy/step -> DPP reduce.
// R2: readlane is int(int,int) — must bitcast.
// R3-R6: compiler collapsed every register prefetch pipeline.
// R7-R9: LDS pipelines stuck ~390us (store drain + 4x LDS pipe re-read).
// R10: asm loads + tied vmcnt(1): 300us; compute hoisted above prefetch.
// R11: PIN pinned compute between load-issue and wait: 234us scan.
// R12 REGRESSION: 2 waves/SIMD halves active CUs; issue > bubble.
// R13 REGRESSION: v_pk_fma_f32 is half issue-rate; packed FP32 != fewer cycles.
// R14 BROKEN: raw back-to-back v_add_f32_dpp hit the VALU->DPP RAW hazard
//     (2 wait states needed; builtin path gets s_nops/scheduling from the
//     compiler, hand asm didn't) -> garbage reduces. NEVER hand-chain DPP.
// R15: builtin DPP reduce restored; keep batched w-update (suffix products)
//     + serial-fma dots; NEW: log2e-space weights (w~ = log2e*w via scaled
//     th0 + scaled W load) -> sigmoid = rcp(1+exp2(-z~)), deleting the
//     per-step v_mul before v_exp (8 insts + ~4cy chain per step).

constexpr int N_IN    = 512;
constexpr int T       = 2048;
constexpr int N_OBS   = 256;
constexpr int D       = 8;            // linearization block size
constexpr int NBLK    = T / D;        // 256
constexpr int BANDPAD = 64;           // packed-band floats per block (28 used)
constexpr float LOG2E = 1.44269504088896f;

typedef float f4 __attribute__((ext_vector_type(4)));

// Packed band layout for block b (t0=8b): entry k = x_{t0+i}.x_{t0+i+j},
// k = BOFF[i] + (j-1), i=0..6, j=1..7-i (28 entries).
__device__ constexpr int BOFF[8] = {0, 7, 13, 18, 22, 25, 27, 28};

// DPP add-reduce step via builtin (old=0 additive identity; compiler handles
// the VALU->DPP hazard slots — R14 lesson).
#define DPP_ADD(v, ctrl, rmask)                                                \
    v += __int_as_float(__builtin_amdgcn_update_dpp(                           \
        0, __float_as_int(v), (ctrl), (rmask), 0xf, false))

__device__ __forceinline__ float wave64_sum_bcast(float v) {
    DPP_ADD(v, 0x111, 0xf); // row_shr:1
    DPP_ADD(v, 0x112, 0xf); // row_shr:2
    DPP_ADD(v, 0x114, 0xf); // row_shr:4
    DPP_ADD(v, 0x118, 0xf); // row_shr:8
    DPP_ADD(v, 0x142, 0xa); // row_bcast:15
    DPP_ADD(v, 0x143, 0xc); // row_bcast:31 -> lane63 = total
    return __int_as_float(__builtin_amdgcn_readlane(__float_as_int(v), 63));
}

// Serial-fma lane-partial dot: 8 insts, one chain (dots are mutually
// independent so chains overlap).
__device__ __forceinline__ float dot8s(const f4& w0, const f4& w1,
                                       const f4& x0, const f4& x1) {
    float p = w0.x * x0.x;
    p = fmaf(w0.y, x0.y, p);
    p = fmaf(w0.z, x0.z, p);
    p = fmaf(w0.w, x0.w, p);
    p = fmaf(w1.x, x1.x, p);
    p = fmaf(w1.y, x1.y, p);
    p = fmaf(w1.z, x1.z, p);
    p = fmaf(w1.w, x1.w, p);
    return p;
}

// ---- explicit-VMEM primitives ---------------------------------------------
#define GLOADX(dst, addr, offstr)                                              \
    asm volatile("global_load_dwordx4 %0, %1, off offset:" offstr              \
                 : "=v"(dst) : "v"(addr))

// Stage one block's 8 x-rows: exactly 16 vmem load issues, program-ordered.
__device__ __forceinline__ void stage16(f4 (&xb)[16], const char* xa) {
    const char* a0 = xa;
    const char* a1 = xa + 4096;
    const char* a2 = xa + 8192;
    const char* a3 = xa + 12288;
    GLOADX(xb[0],  a0, "0");    GLOADX(xb[1],  a0, "1024");
    GLOADX(xb[2],  a0, "2048"); GLOADX(xb[3],  a0, "3072");
    GLOADX(xb[4],  a1, "0");    GLOADX(xb[5],  a1, "1024");
    GLOADX(xb[6],  a1, "2048"); GLOADX(xb[7],  a1, "3072");
    GLOADX(xb[8],  a2, "0");    GLOADX(xb[9],  a2, "1024");
    GLOADX(xb[10], a2, "2048"); GLOADX(xb[11], a2, "3072");
    GLOADX(xb[12], a3, "0");    GLOADX(xb[13], a3, "1024");
    GLOADX(xb[14], a3, "2048"); GLOADX(xb[15], a3, "3072");
}

#define TIEBUF(ins, buf)                                                       \
    asm volatile(ins                                                           \
        : "+v"(buf[0]), "+v"(buf[1]), "+v"(buf[2]),  "+v"(buf[3]),             \
          "+v"(buf[4]), "+v"(buf[5]), "+v"(buf[6]),  "+v"(buf[7]),             \
          "+v"(buf[8]), "+v"(buf[9]), "+v"(buf[10]), "+v"(buf[11]),            \
          "+v"(buf[12]),"+v"(buf[13]),"+v"(buf[14]), "+v"(buf[15]))

// Pin: consumers of buf must schedule after this point (dataflow), and this
// point is after the preceding volatile loads (volatile order). Zero insts.
#define PIN(buf)      TIEBUF("", buf)
// Wait: drain all but the newest N outstanding vmem ops, tying buf's values.
#define WAIT1(buf)    TIEBUF("s_waitcnt vmcnt(1)", buf)
#define WAIT0(buf)    TIEBUF("s_waitcnt vmcnt(0)", buf)

// ---- Kernel 1: packed Gram band, one wave per 8-step block -----------------
__global__ __launch_bounds__(64) void gram_kernel(const float* __restrict__ X,
                                                  float* __restrict__ P) {
    const int b    = blockIdx.x;          // 0..NBLK-1
    const int lane = threadIdx.x;         // 0..63
    const int t0   = b * D;
    const f4* Xv = (const f4*)(X + (long)t0 * N_IN);
    f4 r[8][2];
    #pragma unroll
    for (int i = 0; i < 8; ++i) {
        r[i][0] = Xv[i * (N_IN / 4) + lane * 2 + 0];
        r[i][1] = Xv[i * (N_IN / 4) + lane * 2 + 1];
    }
    float s[28];
    #pragma unroll
    for (int i = 0; i < 7; ++i) {
        #pragma unroll
        for (int j = 1; j <= 7 - i; ++j) {
            s[BOFF[i] + j - 1] =
                wave64_sum_bcast(dot8s(r[i][0], r[i][1], r[i + j][0], r[i + j][1]));
        }
    }
    if (lane == 0) {
        #pragma unroll
        for (int k = 0; k < 28; ++k) P[b * BANDPAD + k] = s[k];
    }
}

// ---- process one block from a register buffer ------------------------------
// All z/q/w quantities are in log2e-scaled space (w~ = log2e*w); y itself is
// exact sigmoid, via y = rcp(1 + 2^(-z~)).
__device__ __forceinline__ void process_block(
    const f4 (&xb)[16], const float (&bs)[28], int t0, int lane, int wave,
    f4& w0, f4& w1, float th0s, float th1, float* __restrict__ out)
{
    // Boundary: q~_d = w~_{t0} . x_{t0+d} (8 independent chains).
    float q[D];
    #pragma unroll
    for (int d = 0; d < D; ++d)
        q[d] = wave64_sum_bcast(dot8s(w0, w1, xb[2 * d], xb[2 * d + 1]));

    // Eight steps: sigmoid + q~ propagation. w~-update deferred (batched).
    float av[D], bv[D];
    float ys = 0.0f;
    float z = q[0];
    #pragma unroll
    for (int i = 0; i < D; ++i) {
        const float y =
            __builtin_amdgcn_rcpf(1.0f + __builtin_amdgcn_exp2f(-z));
        if (lane == i) ys = y;

        const float a = th0s * y;              // a~ = log2e * lr*th0 * y
        const float b = fmaf(th1 * y, y, 1.0f);
        av[i] = a;
        bv[i] = b;

        #pragma unroll
        for (int d = i + 1; d < D; ++d)
            q[d] = fmaf(b, q[d], a * bs[BOFF[i] + (d - i) - 1]);
        if (i < D - 1) z = q[i + 1];
    }

    // Batched w~-update: w' = B*w + sum_i c_i x_i, c_i = a~_i * prod_{j>i} b_j.
    float c[D];
    float sfx = 1.0f;
    #pragma unroll
    for (int i = D - 1; i >= 0; --i) {
        c[i] = av[i] * sfx;
        sfx *= bv[i];
    }
    const float B = sfx;

    f4 acc0, acc1;
    acc0.x = c[0] * xb[0].x;  acc0.y = c[0] * xb[0].y;
    acc0.z = c[0] * xb[0].z;  acc0.w = c[0] * xb[0].w;
    acc1.x = c[0] * xb[1].x;  acc1.y = c[0] * xb[1].y;
    acc1.z = c[0] * xb[1].z;  acc1.w = c[0] * xb[1].w;
    #pragma unroll
    for (int i = 1; i < D; ++i) {
        acc0.x = fmaf(c[i], xb[2 * i].x, acc0.x);
        acc0.y = fmaf(c[i], xb[2 * i].y, acc0.y);
        acc0.z = fmaf(c[i], xb[2 * i].z, acc0.z);
        acc0.w = fmaf(c[i], xb[2 * i].w, acc0.w);
        acc1.x = fmaf(c[i], xb[2 * i + 1].x, acc1.x);
        acc1.y = fmaf(c[i], xb[2 * i + 1].y, acc1.y);
        acc1.z = fmaf(c[i], xb[2 * i + 1].z, acc1.z);
        acc1.w = fmaf(c[i], xb[2 * i + 1].w, acc1.w);
    }
    w0.x = fmaf(B, w0.x, acc0.x);
    w0.y = fmaf(B, w0.y, acc0.y);
    w0.z = fmaf(B, w0.z, acc0.z);
    w0.w = fmaf(B, w0.w, acc0.w);
    w1.x = fmaf(B, w1.x, acc1.x);
    w1.y = fmaf(B, w1.y, acc1.y);
    w1.z = fmaf(B, w1.z, acc1.z);
    w1.w = fmaf(B, w1.w, acc1.w);

    // One batched store: lanes 0..7 write y_0..y_7 (exec-masked). Volatile:
    // stays before the following WAIT1, pinning the y dep-chain with it.
    float* oaddr = out + (size_t)(t0 + lane) * N_OBS + wave;
    asm volatile("s_mov_b64 vcc, exec\n\t"
                 "s_mov_b64 exec, 0xff\n\t"
                 "global_store_dword %0, %1, off\n\t"
                 "s_mov_b64 exec, vcc"
                 :: "v"(oaddr), "v"(ys) : "vcc");
}

__device__ __forceinline__ void load_band(float (&bs)[28], const float* pb) {
    #pragma unroll
    for (int k = 0; k < 28; ++k) bs[k] = pb[k];   // wave-uniform -> s_load
}

// ---- Kernel 2: the scan ----------------------------------------------------
__global__ __launch_bounds__(256, 1) void oja_scan_kernel(
    const float* __restrict__ X,     // [T, N_IN]
    const float* __restrict__ Winit, // [N_OUT, N_IN]
    const float* __restrict__ theta, // [2]
    const int*   __restrict__ obs,   // [N_OBS]
    const float* __restrict__ P,     // [NBLK, BANDPAD] packed band (d_ws)
    float*       __restrict__ out)   // [T, N_OBS]
{
    const int tid  = threadIdx.x;
    const int wid  = tid >> 6;            // 0..3 (1 wave per SIMD)
    const int lane = tid & 63;
    const int wave = blockIdx.x * 4 + wid; // observed-row index; always < 256

    const int row = obs[wave];
    const float lr   = 1.0f / (float)N_IN;
    const float th0s = theta[0] * lr * LOG2E;  // log2e-space a coefficient
    const float th1  = theta[1] * lr;

    // Ownership (R8): lane owns elements [4l,4l+4) and [256+4l,256+4l+4).
    // Weights held in log2e space: w~ = log2e * w.
    const f4* Wv = (const f4*)(Winit + (long)row * N_IN);
    f4 w0 = Wv[lane];
    f4 w1 = Wv[64 + lane];
    w0.x *= LOG2E; w0.y *= LOG2E; w0.z *= LOG2E; w0.w *= LOG2E;
    w1.x *= LOG2E; w1.y *= LOG2E; w1.z *= LOG2E; w1.w *= LOG2E;

    const char* xbase = (const char*)X + (size_t)lane * 16;

    f4 xA[16], xB[16];
    float bsA[28], bsB[28];

    // Prologue: block 0 into A, full drain.
    stage16(xA, xbase);
    load_band(bsA, P);
    WAIT0(xA);

    for (int blk = 0; blk < NBLK; blk += 2) {
        // Half 1: stage blk+1 into B; PIN(A) forces process(A)'s compute
        // after the loads; WAIT1 drains B's 16 loads (issued ~1 block ago),
        // leaving only the newest out-store in flight.
        const int b1 = (blk + 1 < NBLK) ? (blk + 1) : (NBLK - 1);
        stage16(xB, xbase + (size_t)b1 * 16384);
        load_band(bsB, P + (size_t)b1 * BANDPAD);
        PIN(xA);
        process_block(xA, bsA, blk * D, lane, wave, w0, w1, th0s, th1, out);
        WAIT1(xB);

        // Half 2: symmetric.
        const int b2 = (blk + 2 < NBLK) ? (blk + 2) : (NBLK - 1);
        stage16(xA, xbase + (size_t)b2 * 16384);
        load_band(bsA, P + (size_t)b2 * BANDPAD);
        PIN(xB);
        process_block(xB, bsB, (blk + 1) * D, lane, wave, w0, w1, th0s, th1, out);
        WAIT1(xA);
    }
}

extern "C" void kernel_launch(void* const* d_in, const int* in_sizes, int n_in,
                              void* d_out, int out_size, void* d_ws, size_t ws_size,
                              hipStream_t stream) {
    const float* X     = (const float*)d_in[0];
    const float* Winit = (const float*)d_in[1];
    const float* theta = (const float*)d_in[2];
    const int*   obs   = (const int*)d_in[3];
    float*       out   = (float*)d_out;
    float*       P     = (float*)d_ws;   // NBLK*BANDPAD floats = 64 KB

    // Gram band: one wave per block.
    gram_kernel<<<NBLK, 64, 0, stream>>>(X, P);

    // Scan: 64 WGs x 4 waves = 256 waves, one per SIMD on 64 CUs (R11 shape).
    oja_scan_kernel<<<64, 256, 0, stream>>>(X, Winit, theta, obs, P, out);
}